// Round 1
// baseline (85.579 us; speedup 1.0000x reference)
//
#include <hip/hip_runtime.h>

// Problem constants (from reference setup_inputs / OUTPUT_LENGTH)
#define B_SZ 16
#define N_SZ 512
#define C_SZ 512
#define L_SZ 2048

// Kernel 1: per-batch duration cumsum -> timestep->phoneme index map.
// grid = B_SZ blocks, block = N_SZ threads.
__global__ __launch_bounds__(N_SZ) void build_idx_kernel(
    const float* __restrict__ log_durations,  // (B, N, 1)
    int* __restrict__ idx)                    // (B, L) out: phoneme index or -1
{
    __shared__ int s[N_SZ];
    const int b = blockIdx.x;
    const int n = threadIdx.x;

    // dur = floor(2^ld + 1e-4) * (ld > 0), matching the reference math.
    const float ld = log_durations[b * N_SZ + n];
    int dur = 0;
    if (ld > 0.0f) dur = (int)floorf(exp2f(ld) + 1e-4f);

    // Inclusive Hillis-Steele scan over 512 elements in LDS (9 steps).
    s[n] = dur;
    __syncthreads();
    #pragma unroll
    for (int off = 1; off < N_SZ; off <<= 1) {
        int add = (n >= off) ? s[n - off] : 0;
        __syncthreads();
        s[n] += add;
        __syncthreads();
    }

    const int end   = s[n];
    const int start = end - dur;

    // Scatter: idx[b, start..end) = n  (clamped to L)
    if (start < L_SZ) {
        const int e = min(end, L_SZ);
        for (int t = start; t < e; ++t) idx[b * L_SZ + t] = n;
    }

    // Tail: idx[b, total..L) = -1
    const int total = min(s[N_SZ - 1], L_SZ);
    for (int t = total + n; t < L_SZ; t += N_SZ) idx[b * L_SZ + t] = -1;
}

// Kernel 2: out[b, l, :] = (p >= 0) ? enc[b, p, :] : 0
// grid = B_SZ * L_SZ blocks (one per output row), block = C_SZ/4 = 128 threads,
// float4 per lane -> 2 KB coalesced copy per block.
__global__ __launch_bounds__(C_SZ / 4) void gather_kernel(
    const float4* __restrict__ enc,   // (B, N, C) as float4
    const int*    __restrict__ idx,   // (B, L)
    float4*       __restrict__ out)   // (B, L, C) as float4
{
    const int row = blockIdx.x;        // b * L + l
    const int b   = row >> 11;         // L = 2048
    const int p   = idx[row];
    const int c4  = threadIdx.x;       // 0..127

    float4 v;
    if (p >= 0) {
        v = enc[(size_t)(b * N_SZ + p) * (C_SZ / 4) + c4];
    } else {
        v = make_float4(0.f, 0.f, 0.f, 0.f);
    }
    out[(size_t)row * (C_SZ / 4) + c4] = v;
}

extern "C" void kernel_launch(void* const* d_in, const int* in_sizes, int n_in,
                              void* d_out, int out_size, void* d_ws, size_t ws_size,
                              hipStream_t stream) {
    const float* enc = (const float*)d_in[0];          // (16, 512, 512) fp32
    const float* ld  = (const float*)d_in[1];          // (16, 512, 1)  fp32
    float* out       = (float*)d_out;                  // (16, 2048, 512) fp32
    int* idx         = (int*)d_ws;                     // B*L ints = 128 KB scratch

    build_idx_kernel<<<B_SZ, N_SZ, 0, stream>>>(ld, idx);
    gather_kernel<<<B_SZ * L_SZ, C_SZ / 4, 0, stream>>>(
        (const float4*)enc, idx, (float4*)out);
}

// Round 2
// 83.256 us; speedup vs baseline: 1.0279x; 1.0279x over previous
//
#include <hip/hip_runtime.h>

// Problem constants (from reference setup_inputs / OUTPUT_LENGTH)
#define B_SZ 16
#define N_SZ 512
#define C_SZ 512
#define L_SZ 2048
#define ROW4 (C_SZ / 4)              // 128 float4 per output row
#define TOTAL4 (B_SZ * L_SZ * ROW4)  // 4,194,304 float4 elements

// ---------------------------------------------------------------------------
// Kernel 1: per-batch duration cumsum -> timestep->phoneme index map.
// grid = B_SZ blocks, block = N_SZ threads. One barrier total (wave-shuffle
// scan inside each 64-lane wave, tiny LDS combine across the 8 waves).
// ---------------------------------------------------------------------------
__global__ __launch_bounds__(N_SZ) void build_idx_kernel(
    const float* __restrict__ log_durations,  // (B, N, 1)
    int* __restrict__ idx)                    // (B, L) out: phoneme index or -1
{
    __shared__ int wsum[8];
    const int b    = blockIdx.x;
    const int n    = threadIdx.x;
    const int lane = n & 63;
    const int w    = n >> 6;

    // dur = floor(2^ld + 1e-4) * (ld > 0), matching the reference math.
    const float ld = log_durations[b * N_SZ + n];
    int dur = 0;
    if (ld > 0.0f) dur = (int)floorf(exp2f(ld) + 1e-4f);

    // Inclusive scan within the 64-lane wave (no barriers).
    int scan = dur;
    #pragma unroll
    for (int o = 1; o < 64; o <<= 1) {
        int v = __shfl_up(scan, o, 64);
        if (lane >= o) scan += v;
    }
    if (lane == 63) wsum[w] = scan;
    __syncthreads();

    // Add exclusive prefix of wave totals; also grab grand total.
    int base = 0, total = 0;
    #pragma unroll
    for (int i = 0; i < 8; ++i) {
        const int s = wsum[i];     // LDS broadcast, conflict-free
        if (i < w) base += s;
        total += s;
    }
    const int end   = base + scan;
    const int start = end - dur;

    // Scatter: idx[b, start..end) = n  (clamped to L). Durations are small
    // (floor(2^N(0,1)) -> mostly 1-3), so this loop is short.
    if (start < L_SZ) {
        const int e = min(end, L_SZ);
        for (int t = start; t < e; ++t) idx[b * L_SZ + t] = n;
    }

    // Tail: idx[b, total..L) = -1
    const int tmin = min(total, L_SZ);
    for (int t = tmin + n; t < L_SZ; t += N_SZ) idx[b * L_SZ + t] = -1;
}

// ---------------------------------------------------------------------------
// Kernel 2: out[b, l, :] = (p >= 0) ? enc[b, p, :] : 0
// grid = 2048 blocks x 256 threads; each thread does exactly 8 independent
// float4 copy iterations (stride 2048*256), fully unrolled for MLP.
// ---------------------------------------------------------------------------
#define G_BLOCKS 2048
#define G_THREADS 256
#define G_STRIDE (G_BLOCKS * G_THREADS)        // 524,288
#define G_ITERS (TOTAL4 / G_STRIDE)            // 8 exactly

__global__ __launch_bounds__(G_THREADS) void gather_kernel(
    const float4* __restrict__ enc,   // (B, N, C) as float4
    const int*    __restrict__ idx,   // (B, L)
    float4*       __restrict__ out)   // (B, L, C) as float4
{
    const int g0 = blockIdx.x * G_THREADS + threadIdx.x;
    #pragma unroll
    for (int it = 0; it < G_ITERS; ++it) {
        const int g   = g0 + it * G_STRIDE;
        const int row = g >> 7;        // /ROW4
        const int b   = row >> 11;     // /L_SZ
        const int c4  = g & (ROW4 - 1);
        const int p   = idx[row];      // wave-uniform per half-row, L1/L2 hit
        float4 v = make_float4(0.f, 0.f, 0.f, 0.f);
        if (p >= 0) v = enc[(size_t)((b << 9) + p) * ROW4 + c4];
        out[g] = v;
    }
}

extern "C" void kernel_launch(void* const* d_in, const int* in_sizes, int n_in,
                              void* d_out, int out_size, void* d_ws, size_t ws_size,
                              hipStream_t stream) {
    const float* enc = (const float*)d_in[0];          // (16, 512, 512) fp32
    const float* ld  = (const float*)d_in[1];          // (16, 512, 1)  fp32
    float* out       = (float*)d_out;                  // (16, 2048, 512) fp32
    int* idx         = (int*)d_ws;                     // B*L ints = 128 KB scratch

    build_idx_kernel<<<B_SZ, N_SZ, 0, stream>>>(ld, idx);
    gather_kernel<<<G_BLOCKS, G_THREADS, 0, stream>>>(
        (const float4*)enc, idx, (float4*)out);
}